// Round 2
// baseline (2986.964 us; speedup 1.0000x reference)
//
#include <hip/hip_runtime.h>
#include <math.h>

#define DD 768
#define PP 576
#define BB 32
#define NROW (BB*PP)     // 18432
#define NA 16
#define NFP 64
#define KSEL 8
#define NEGV -1000000000.0

// ---- workspace BYTE offsets ----
#define OFFB_QK64     0ull            // 18432*1536*8 = 226492416
#define OFFB_SC64     226492416ull    // 32*576*576*8 = 84934656
#define OFFB_V32      311427072ull    // 18432*768*4 = 56623104
#define OFFB_WEQK64   368050176ull    // 768*1536*8 = 9437184
#define OFFB_WEV32    377487360ull    // 768*768*4
#define OFFB_WOT32    379846656ull    // 768*768*4
#define OFFB_CN64     382205952ull    // 576*8
#define OFFB_BIASQK64 382210560ull    // 1536*8
#define OFFB_BIASV32  382222848ull    // 768*4
#define OFFB_SCAL32   382225920ull    // 16*4
#define OFFB_FPB32    382225984ull    // 16*4
#define OFFB_POOL32   382226048ull    // 32*768*4
#define OFFB_FEAT32   382324352ull
#define OFFB_ANCN32   382422656ull    // 16*768*4
#define OFFB_AFFS32   382471808ull
#define OFFB_AAFF32   382473856ull
#define OFFB_PREDS32  382475904ull    // 32*16*768*4
#define OFFB_ANCO32   384048768ull
#define OFFB_ROUTED32 0ull            // aliases QK64 (dead after scores GEMM)
// total = 384147072 bytes (~366 MB)

// ---- d_out float offsets ----
#define OUT_ROUTES  0
#define OUT_WEIGHTS 147456
#define OUT_OUT     294912

__device__ __forceinline__ float wave_sum_f(float v) {
#pragma unroll
    for (int off = 32; off > 0; off >>= 1) v += __shfl_xor(v, off);
    return v;
}
__device__ __forceinline__ double wave_sum_d(double v) {
#pragma unroll
    for (int off = 32; off > 0; off >>= 1) v += __shfl_xor(v, off);
    return v;
}

// ---------------------------------------------------------------------------
// 1a) W_eff for q,k in f64: weff[d*1536 + m*768 + j] = W[j,d] + 0.1*(Wm[e]·f + bm[e])
// ---------------------------------------------------------------------------
__global__ void k_weffqk64(const float* __restrict__ Wq, const float* __restrict__ Wk,
                           const float* __restrict__ Wqm, const float* __restrict__ Wkm,
                           const float* __restrict__ bqm, const float* __restrict__ bkm,
                           const float* __restrict__ fp, double* __restrict__ weff)
{
    int gid = blockIdx.x * 256 + threadIdx.x;   // < 2*589824
    int m = gid / (DD * DD);
    int e = gid - m * (DD * DD);
    const float* Wm = m ? Wkm : Wqm;
    const float* bm = m ? bkm : bqm;
    const float* W  = m ? Wk  : Wq;
    int d = e / DD, j = e - d * DD;
    const float4* wrow = (const float4*)(Wm + (size_t)e * NFP);
    const float4* f4 = (const float4*)fp;
    double dot = 0.0;
#pragma unroll
    for (int i = 0; i < 16; i++) {
        float4 a = wrow[i]; float4 b = f4[i];
        dot += (double)a.x * (double)b.x + (double)a.y * (double)b.y
             + (double)a.z * (double)b.z + (double)a.w * (double)b.w;
    }
    weff[(size_t)d * 1536 + m * DD + j] = (double)W[(size_t)j * DD + d] + 0.1 * (dot + (double)bm[e]);
}

// ---------------------------------------------------------------------------
// 1b) W_eff for v in f32
// ---------------------------------------------------------------------------
__global__ void k_weffv32(const float* __restrict__ Wv, const float* __restrict__ Wvm,
                          const float* __restrict__ bvm, const float* __restrict__ fp,
                          float* __restrict__ weff)
{
    int e = blockIdx.x * 256 + threadIdx.x;     // < 589824
    int d = e / DD, j = e - d * DD;
    const float4* wrow = (const float4*)(Wvm + (size_t)e * NFP);
    const float4* f4 = (const float4*)fp;
    float dot = 0.f;
#pragma unroll
    for (int i = 0; i < 16; i++) {
        float4 a = wrow[i]; float4 b = f4[i];
        dot += a.x * b.x + a.y * b.y + a.z * b.z + a.w * b.w;
    }
    weff[(size_t)d * DD + j] = Wv[(size_t)j * DD + d] + 0.1f * (dot + bvm[e]);
}

// ---------------------------------------------------------------------------
// 2) setup: cnorm (f64), biases, fp_bias, sigmoid(aw)
// ---------------------------------------------------------------------------
__global__ void k_setup64(const float* __restrict__ fp,
                          const float* __restrict__ Wfo, const float* __restrict__ bfo,
                          const float* __restrict__ Wab, const float* __restrict__ bab,
                          const float* __restrict__ bq, const float* __restrict__ bk,
                          const float* __restrict__ bv,
                          const float* __restrict__ aw, char* __restrict__ ws)
{
    double* cn = (double*)(ws + OFFB_CN64);
    double* biasqk = (double*)(ws + OFFB_BIASQK64);
    float* biasv = (float*)(ws + OFFB_BIASV32);
    float* scal = (float*)(ws + OFFB_SCAL32);
    float* fpb = (float*)(ws + OFFB_FPB32);
    __shared__ double shp[2];
    __shared__ double shc[PP];
    int t = threadIdx.x;
    if (t < 2) {
        double s = 0.0;
        for (int i = 0; i < NFP; i++) s += (double)Wfo[t * NFP + i] * (double)fp[i];
        shp[t] = s + (double)bfo[t];
    }
    if (t == 2) scal[0] = (float)(1.0 / (1.0 + exp(-(double)aw[0])));
    if (t >= 4 && t < 20) {
        int a = t - 4;
        float s = 0.f;
        for (int i = 0; i < NFP; i++) s += Wab[a * NFP + i] * fp[i];
        fpb[a] = s + bab[a];
    }
    for (int i = t; i < 1536; i += 640) biasqk[i] = (double)((i < DD) ? bq[i] : bk[i - DD]);
    for (int i = t; i < DD; i += 640) biasv[i] = bv[i];
    __syncthreads();
    double scale = 2.0 / (1.0 + exp(-shp[0])) + 0.5;
    double shift = tanh(shp[1]) * 24.0;
    if (t < PP) {
        int xg = t % 24, yg = t / 24;
        int s = xg + yg;
        double cant = (double)(s * (s + 1) / 2 + yg);
        shc[t] = cant * scale + shift;
    }
    __syncthreads();
    if (t == 0) {
        double mx = shc[0];
        for (int i = 1; i < PP; i++) mx = fmax(mx, shc[i]);
        shp[0] = fmax(mx, 1.0);
    }
    __syncthreads();
    if (t < PP) cn[t] = shc[t] / shp[0];
}

// ---------------------------------------------------------------------------
// 3) l2-normalize anchor_embeds rows (f32; anchor path only)
// ---------------------------------------------------------------------------
__global__ void k_anchors(const float* __restrict__ ae, float* __restrict__ ancn)
{
    int a = blockIdx.x, lane = threadIdx.x;
    const float4* row = (const float4*)(ae + (size_t)a * DD);
    float4 v[3]; float ss = 0.f;
#pragma unroll
    for (int c = 0; c < 3; c++) {
        v[c] = row[c * 64 + lane];
        ss += v[c].x * v[c].x + v[c].y * v[c].y + v[c].z * v[c].z + v[c].w * v[c].w;
    }
    ss = wave_sum_f(ss);
    float den = fmaxf(sqrtf(ss), 1e-12f);
    float4* o = (float4*)(ancn + (size_t)a * DD);
#pragma unroll
    for (int c = 0; c < 3; c++)
        o[c * 64 + lane] = make_float4(v[c].x / den, v[c].y / den, v[c].z / den, v[c].w / den);
}

// ---------------------------------------------------------------------------
// 4) q,k GEMM in f64: qk(18432x1536) = patches(f32->f64) @ weffqk64 + bias
//    64x64x16 tile, 256 thr, 4x4 micro
// ---------------------------------------------------------------------------
__launch_bounds__(256)
__global__ void k_gemm_qk64(const float* __restrict__ x, const double* __restrict__ weff,
                            const double* __restrict__ bias, double* __restrict__ qk)
{
    __shared__ double As[16][66];
    __shared__ double Bs[16][66];
    const int tid = threadIdx.x;
    const int n0 = blockIdx.x * 64;
    const int row0 = blockIdx.y * 64;
    const int lr = tid >> 2;            // 0..63
    const int kc = (tid & 3) * 4;       // 0,4,8,12
    const int r = row0 + lr;
    const float* pA = x + (size_t)(r + r / PP + 1) * DD + kc;
    const int bkr = tid >> 4;           // 0..15 (k row)
    const int bcol = (tid & 15) * 4;    // 0..60
    const double* pB = weff + (size_t)bkr * 1536 + n0 + bcol;
    const int tx = tid & 15, ty = tid >> 4;
    double acc[4][4];
#pragma unroll
    for (int i = 0; i < 4; i++)
#pragma unroll
        for (int j = 0; j < 4; j++) acc[i][j] = 0.0;

    for (int k0 = 0; k0 < DD; k0 += 16) {
        float4 a = *(const float4*)(pA + k0);
        double2 b0 = *(const double2*)(pB + (size_t)k0 * 1536);
        double2 b1 = *(const double2*)(pB + (size_t)k0 * 1536 + 2);
        __syncthreads();
        As[kc + 0][lr] = (double)a.x; As[kc + 1][lr] = (double)a.y;
        As[kc + 2][lr] = (double)a.z; As[kc + 3][lr] = (double)a.w;
        *(double2*)&Bs[bkr][bcol] = b0;
        *(double2*)&Bs[bkr][bcol + 2] = b1;
        __syncthreads();
#pragma unroll
        for (int k = 0; k < 16; k++) {
            double2 a01 = *(const double2*)&As[k][ty * 4];
            double2 a23 = *(const double2*)&As[k][ty * 4 + 2];
            double2 b01 = *(const double2*)&Bs[k][tx * 4];
            double2 b23 = *(const double2*)&Bs[k][tx * 4 + 2];
            double av[4] = {a01.x, a01.y, a23.x, a23.y};
            double bv[4] = {b01.x, b01.y, b23.x, b23.y};
#pragma unroll
            for (int i = 0; i < 4; i++)
#pragma unroll
                for (int j = 0; j < 4; j++) acc[i][j] = fma(av[i], bv[j], acc[i][j]);
        }
    }
#pragma unroll
    for (int i = 0; i < 4; i++) {
        int rr = row0 + ty * 4 + i;
        double* op = qk + (size_t)rr * 1536 + n0 + tx * 4;
#pragma unroll
        for (int j = 0; j < 4; j++) op[j] = acc[i][j] + bias[n0 + tx * 4 + j];
    }
}

// ---------------------------------------------------------------------------
// 5) f64 l2-normalize q,k rows in-place (wave per (row,mat))
// ---------------------------------------------------------------------------
__launch_bounds__(256)
__global__ void k_norm64(double* __restrict__ qk)
{
    const int tid = threadIdx.x, wv = tid >> 6, lane = tid & 63;
    const int task = blockIdx.x * 4 + wv;     // < 36864
    const int row = task >> 1, mat = task & 1;
    double2* p = (double2*)(qk + (size_t)row * 1536 + mat * DD);
    double2 v[6]; double ss = 0.0;
#pragma unroll
    for (int c = 0; c < 6; c++) {
        v[c] = p[c * 64 + lane];
        ss += v[c].x * v[c].x + v[c].y * v[c].y;
    }
    ss = wave_sum_d(ss);
    double den = fmax(sqrt(ss), 1e-12);
#pragma unroll
    for (int c = 0; c < 6; c++) {
        v[c].x /= den; v[c].y /= den;
        p[c * 64 + lane] = v[c];
    }
}

// ---------------------------------------------------------------------------
// 6) v GEMM f32: v(18432x768) = patches @ weffv + bv  (128x128x16, 8x8 micro)
// ---------------------------------------------------------------------------
__launch_bounds__(256)
__global__ void k_gemm_v32(const float* __restrict__ x, const float* __restrict__ weff,
                           const float* __restrict__ biasv, float* __restrict__ vout)
{
    __shared__ float As[16][132];
    __shared__ float Bs[16][132];
    const int tid = threadIdx.x;
    const int n0 = blockIdx.x * 128;
    const int row0 = blockIdx.y * 128;
    const int lr = tid >> 2;
    const int kc = (tid & 3) * 4;
    const int r1 = row0 + lr, r2 = r1 + 64;
    const float* pA1 = x + (size_t)(r1 + r1 / PP + 1) * DD + kc;
    const float* pA2 = x + (size_t)(r2 + r2 / PP + 1) * DD + kc;
    const int bkr = tid >> 5;
    const int bcol = (tid & 31) * 4;
    const float* pB1 = weff + (size_t)bkr * DD + n0 + bcol;
    const float* pB2 = weff + (size_t)(bkr + 8) * DD + n0 + bcol;
    const int tx = tid & 15, ty = tid >> 4;
    float acc[8][8];
#pragma unroll
    for (int i = 0; i < 8; i++)
#pragma unroll
        for (int j = 0; j < 8; j++) acc[i][j] = 0.f;

    for (int k0 = 0; k0 < DD; k0 += 16) {
        float4 a1 = *(const float4*)(pA1 + k0);
        float4 a2 = *(const float4*)(pA2 + k0);
        float4 b1 = *(const float4*)(pB1 + (size_t)k0 * DD);
        float4 b2 = *(const float4*)(pB2 + (size_t)k0 * DD);
        __syncthreads();
        As[kc + 0][lr] = a1.x; As[kc + 1][lr] = a1.y; As[kc + 2][lr] = a1.z; As[kc + 3][lr] = a1.w;
        As[kc + 0][64 + lr] = a2.x; As[kc + 1][64 + lr] = a2.y; As[kc + 2][64 + lr] = a2.z; As[kc + 3][64 + lr] = a2.w;
        *(float4*)&Bs[bkr][bcol] = b1;
        *(float4*)&Bs[bkr + 8][bcol] = b2;
        __syncthreads();
#pragma unroll
        for (int k = 0; k < 16; k++) {
            float4 a0 = *(const float4*)&As[k][ty * 8];
            float4 a1v = *(const float4*)&As[k][ty * 8 + 4];
            float4 b0 = *(const float4*)&Bs[k][tx * 8];
            float4 b1v = *(const float4*)&Bs[k][tx * 8 + 4];
            float av[8] = {a0.x, a0.y, a0.z, a0.w, a1v.x, a1v.y, a1v.z, a1v.w};
            float bv[8] = {b0.x, b0.y, b0.z, b0.w, b1v.x, b1v.y, b1v.z, b1v.w};
#pragma unroll
            for (int i = 0; i < 8; i++)
#pragma unroll
                for (int j = 0; j < 8; j++) acc[i][j] += av[i] * bv[j];
        }
    }
    float bb_[8];
#pragma unroll
    for (int j = 0; j < 8; j++) bb_[j] = biasv[n0 + tx * 8 + j];
#pragma unroll
    for (int i = 0; i < 8; i++) {
        int rr = row0 + ty * 8 + i;
        float* op = vout + (size_t)rr * DD + n0 + tx * 8;
        *(float4*)op = make_float4(acc[i][0] + bb_[0], acc[i][1] + bb_[1],
                                   acc[i][2] + bb_[2], acc[i][3] + bb_[3]);
        *(float4*)(op + 4) = make_float4(acc[i][4] + bb_[4], acc[i][5] + bb_[5],
                                         acc[i][6] + bb_[6], acc[i][7] + bb_[7]);
    }
}

// ---------------------------------------------------------------------------
// 7) scores GEMM f64 per batch: qn @ kn^T + 0.3*(1-|cn_p-cn_j|), diag NEG
// ---------------------------------------------------------------------------
__launch_bounds__(256)
__global__ void k_gemm_scores64(const double* __restrict__ qk, const double* __restrict__ cn,
                                double* __restrict__ scores)
{
    __shared__ double As[16][66];
    __shared__ double Bs[16][66];
    const int bz = blockIdx.z;
    const int row0 = blockIdx.y * 64, col0 = blockIdx.x * 64;
    const int tid = threadIdx.x;
    const int lr = tid >> 2;
    const int kc = (tid & 3) * 4;
    const double* pA = qk + (size_t)(bz * PP + row0 + lr) * 1536 + kc;        // q
    const double* pB = qk + (size_t)(bz * PP + col0 + lr) * 1536 + DD + kc;   // k
    const int tx = tid & 15, ty = tid >> 4;
    double acc[4][4];
#pragma unroll
    for (int i = 0; i < 4; i++)
#pragma unroll
        for (int j = 0; j < 4; j++) acc[i][j] = 0.0;

    for (int k0 = 0; k0 < DD; k0 += 16) {
        double2 a0 = *(const double2*)(pA + k0);
        double2 a1 = *(const double2*)(pA + k0 + 2);
        double2 b0 = *(const double2*)(pB + k0);
        double2 b1 = *(const double2*)(pB + k0 + 2);
        __syncthreads();
        As[kc + 0][lr] = a0.x; As[kc + 1][lr] = a0.y; As[kc + 2][lr] = a1.x; As[kc + 3][lr] = a1.y;
        Bs[kc + 0][lr] = b0.x; Bs[kc + 1][lr] = b0.y; Bs[kc + 2][lr] = b1.x; Bs[kc + 3][lr] = b1.y;
        __syncthreads();
#pragma unroll
        for (int k = 0; k < 16; k++) {
            double2 a01 = *(const double2*)&As[k][ty * 4];
            double2 a23 = *(const double2*)&As[k][ty * 4 + 2];
            double2 b01 = *(const double2*)&Bs[k][tx * 4];
            double2 b23 = *(const double2*)&Bs[k][tx * 4 + 2];
            double av[4] = {a01.x, a01.y, a23.x, a23.y};
            double bv[4] = {b01.x, b01.y, b23.x, b23.y};
#pragma unroll
            for (int i = 0; i < 4; i++)
#pragma unroll
                for (int j = 0; j < 4; j++) acc[i][j] = fma(av[i], bv[j], acc[i][j]);
        }
    }
#pragma unroll
    for (int i = 0; i < 4; i++) {
        int p = row0 + ty * 4 + i;
        double cp = cn[p];
        double* op = scores + ((size_t)bz * PP + p) * PP + col0 + tx * 4;
#pragma unroll
        for (int j = 0; j < 4; j++) {
            int jj = col0 + tx * 4 + j;
            double s = acc[i][j] + 0.3 * (1.0 - fabs(cp - cn[jj]));
            op[j] = (p == jj) ? NEGV : s;
        }
    }
}

// ---------------------------------------------------------------------------
// 8) top-k=8 f64 (stable ties), f64 softmax, routed gather (wave per row)
// ---------------------------------------------------------------------------
__launch_bounds__(256)
__global__ void k_topk64(const double* __restrict__ scores, const float* __restrict__ v32,
                         float* __restrict__ routed, float* __restrict__ dout)
{
    const int tid = threadIdx.x;
    const int wv = tid >> 6, lane = tid & 63;
    const int row = blockIdx.x * 4 + wv;
    const int b = row / PP;
    const double* srow = scores + (size_t)row * PP;
    double cand[9];
#pragma unroll
    for (int c = 0; c < 9; c++) cand[c] = srow[c * 64 + lane] / 0.1;   // scores/TEMP, f64
    double vals[8]; int idxs[8];
#pragma unroll
    for (int k = 0; k < KSEL; k++) {
        double bvv = -1.0e300; int bj = 1 << 29;
#pragma unroll
        for (int c = 0; c < 9; c++) {
            if (cand[c] > bvv) { bvv = cand[c]; bj = c * 64 + lane; }
        }
#pragma unroll
        for (int off = 32; off > 0; off >>= 1) {
            double ov = __shfl_xor(bvv, off);
            int oj = __shfl_xor(bj, off);
            if (ov > bvv || (ov == bvv && oj < bj)) { bvv = ov; bj = oj; }
        }
        vals[k] = bvv; idxs[k] = bj;
        int slot = bj >> 6;
#pragma unroll
        for (int c = 0; c < 9; c++)
            if (c == slot && (bj & 63) == lane) cand[c] = -1.0e300;
    }
    double mx = vals[0];
    double e[8]; double s = 0.0;
#pragma unroll
    for (int k = 0; k < 8; k++) { e[k] = exp(vals[k] - mx); s += e[k]; }
    float w8[8];
#pragma unroll
    for (int k = 0; k < 8; k++) {
        w8[k] = (float)(e[k] / s);
        if (lane == k) {
            dout[OUT_ROUTES + (size_t)row * 8 + k] = (float)idxs[k];
            dout[OUT_WEIGHTS + (size_t)row * 8 + k] = w8[k];
        }
    }
    float4 av[3];
#pragma unroll
    for (int c = 0; c < 3; c++) av[c] = make_float4(0.f, 0.f, 0.f, 0.f);
#pragma unroll
    for (int k = 0; k < 8; k++) {
        float w = w8[k];
        const float4* vr = (const float4*)(v32 + (size_t)(b * PP + idxs[k]) * DD);
#pragma unroll
        for (int c = 0; c < 3; c++) {
            float4 vv = vr[c * 64 + lane];
            av[c].x += w * vv.x; av[c].y += w * vv.y; av[c].z += w * vv.z; av[c].w += w * vv.w;
        }
    }
    float4* orow = (float4*)(routed + (size_t)row * DD);
#pragma unroll
    for (int c = 0; c < 3; c++) orow[c * 64 + lane] = av[c];
}

// ---------------------------------------------------------------------------
// 9) pooled = mean over patches
// ---------------------------------------------------------------------------
__global__ void k_pooled(const float* __restrict__ x, float* __restrict__ pooled)
{
    int b = blockIdx.y;
    int d = blockIdx.x * 256 + threadIdx.x;
    const float* base = x + ((size_t)b * 577 + 1) * DD + d;
    float s = 0.f;
    for (int p = 0; p < PP; p++) s += base[(size_t)p * DD];
    pooled[b * DD + d] = s / 576.0f;
}

// ---------------------------------------------------------------------------
// 10) feat_proj = l2(pooled @ Wfp.T + bfp)
// ---------------------------------------------------------------------------
__global__ void k_featproj(const float* __restrict__ pooled, const float* __restrict__ Wfp,
                           const float* __restrict__ bfp, float* __restrict__ feat)
{
    __shared__ float ps[DD];
    __shared__ float red[256];
    int b = blockIdx.x, t = threadIdx.x;
    for (int i = t; i < DD; i += 256) ps[i] = pooled[b * DD + i];
    __syncthreads();
    float out[3]; float ss = 0.f;
#pragma unroll
    for (int c = 0; c < 3; c++) {
        int j = c * 256 + t;
        const float4* wr = (const float4*)(Wfp + (size_t)j * DD);
        float s = 0.f;
        for (int i = 0; i < 192; i++) {
            float4 w4 = wr[i];
            s += ps[4 * i] * w4.x + ps[4 * i + 1] * w4.y + ps[4 * i + 2] * w4.z + ps[4 * i + 3] * w4.w;
        }
        s += bfp[j];
        out[c] = s; ss += s * s;
    }
    red[t] = ss; __syncthreads();
    for (int st = 128; st > 0; st >>= 1) {
        if (t < st) red[t] += red[t + st];
        __syncthreads();
    }
    float den = fmaxf(sqrtf(red[0]), 1e-12f);
#pragma unroll
    for (int c = 0; c < 3; c++) feat[b * DD + c * 256 + t] = out[c] / den;
}

// ---------------------------------------------------------------------------
// 11) anchor affinity + softmax
// ---------------------------------------------------------------------------
__global__ void k_affs(const float* __restrict__ feat, const float* __restrict__ ancn,
                       const float* __restrict__ fpb, float* __restrict__ affs)
{
    int tid = threadIdx.x, wv = tid >> 6, lane = tid & 63;
    int wid = blockIdx.x * 4 + wv;
    int b = wid >> 4, a = wid & 15;
    const float4* f4 = (const float4*)(feat + (size_t)b * DD);
    const float4* a4 = (const float4*)(ancn + (size_t)a * DD);
    float s = 0.f;
#pragma unroll
    for (int c = 0; c < 3; c++) {
        float4 fv = f4[c * 64 + lane], av = a4[c * 64 + lane];
        s += fv.x * av.x + fv.y * av.y + fv.z * av.z + fv.w * av.w;
    }
    s = wave_sum_f(s);
    if (lane == 0) affs[b * NA + a] = s + 0.3f * fpb[a];
}

__global__ void k_affsm(const float* __restrict__ affs, float* __restrict__ aaff)
{
    int b = blockIdx.x, lane = threadIdx.x;
    float v = affs[b * NA + (lane & 15)];
    float m = v;
#pragma unroll
    for (int off = 8; off > 0; off >>= 1) m = fmaxf(m, __shfl_xor(m, off));
    float e = expf(v - m);
    float s = e;
#pragma unroll
    for (int off = 8; off > 0; off >>= 1) s += __shfl_xor(s, off);
    if (lane < NA) aaff[b * NA + lane] = e / s;
}

// ---------------------------------------------------------------------------
// 12) anchor_preds[b,a,e] = pooled[b]·AW[a,e,:]
// ---------------------------------------------------------------------------
__launch_bounds__(256)
__global__ void k_preds(const float* __restrict__ pooled, const float* __restrict__ AW,
                        float* __restrict__ preds)
{
    __shared__ float AWs[64][65];
    __shared__ float ps[32][65];
    const int a = blockIdx.y;
    const int e0 = blockIdx.x * 64;
    const int t = threadIdx.x;
    const int eloc = t & 63, bgrp = t >> 6;
    float acc[8];
#pragma unroll
    for (int i = 0; i < 8; i++) acc[i] = 0.f;
    for (int d0 = 0; d0 < DD; d0 += 64) {
        __syncthreads();
#pragma unroll
        for (int i = 0; i < 16; i++) {
            int lin = t + i * 256;
            int ei = lin >> 6, dd = lin & 63;
            AWs[ei][dd] = AW[((size_t)a * DD + e0 + ei) * DD + d0 + dd];
        }
#pragma unroll
        for (int i = 0; i < 8; i++) {
            int lin = t + i * 256;
            int bb2 = lin >> 6, dd = lin & 63;
            ps[bb2][dd] = pooled[bb2 * DD + d0 + dd];
        }
        __syncthreads();
        for (int dd = 0; dd < 64; dd++) {
            float w = AWs[eloc][dd];
#pragma unroll
            for (int bb2 = 0; bb2 < 8; bb2++) acc[bb2] += ps[bgrp * 8 + bb2][dd] * w;
        }
    }
#pragma unroll
    for (int bb2 = 0; bb2 < 8; bb2++)
        preds[((size_t)(bgrp * 8 + bb2) * NA + a) * DD + e0 + eloc] = acc[bb2];
}

// ---------------------------------------------------------------------------
// 13) anchor_out[b,e] = sum_a aaff[b,a]*preds[b,a,e]
// ---------------------------------------------------------------------------
__global__ void k_anco(const float* __restrict__ preds, const float* __restrict__ aaff,
                       float* __restrict__ anco)
{
    int b = blockIdx.y;
    int e = blockIdx.x * 256 + threadIdx.x;
    float s = 0.f;
#pragma unroll
    for (int a = 0; a < NA; a++) s += aaff[b * NA + a] * preds[((size_t)b * NA + a) * DD + e];
    anco[b * DD + e] = s;
}

// ---------------------------------------------------------------------------
// 14) transpose Wo
// ---------------------------------------------------------------------------
__global__ void k_wot(const float* __restrict__ Wo, float* __restrict__ wot)
{
    __shared__ float tile[32][33];
    int tx = threadIdx.x, ty = threadIdx.y;
    int j0 = blockIdx.y * 32, d0 = blockIdx.x * 32;
#pragma unroll
    for (int i = 0; i < 4; i++) tile[ty + i * 8][tx] = Wo[(size_t)(j0 + ty + i * 8) * DD + d0 + tx];
    __syncthreads();
#pragma unroll
    for (int i = 0; i < 4; i++) wot[(size_t)(d0 + ty + i * 8) * DD + j0 + tx] = tile[tx][ty + i * 8];
}

// ---------------------------------------------------------------------------
// 15) out GEMM: routed @ WoT + bo + patches + sig*anchor_out
// ---------------------------------------------------------------------------
__launch_bounds__(256)
__global__ void k_gemm_out(const float* __restrict__ routed, const float* __restrict__ wot,
                           const float* __restrict__ bo, const float* __restrict__ x,
                           const float* __restrict__ anco, const float* __restrict__ scal,
                           float* __restrict__ dout)
{
    __shared__ float As[16][132];
    __shared__ float Bs[16][132];
    const int tid = threadIdx.x;
    const int n0 = blockIdx.x * 128;
    const int row0 = blockIdx.y * 128;
    const int lr = tid >> 2;
    const int kc = (tid & 3) * 4;
    const float* pA1 = routed + (size_t)(row0 + lr) * DD + kc;
    const float* pA2 = routed + (size_t)(row0 + 64 + lr) * DD + kc;
    const int bkr = tid >> 5;
    const int bcol = (tid & 31) * 4;
    const float* pB1 = wot + (size_t)bkr * DD + n0 + bcol;
    const float* pB2 = wot + (size_t)(bkr + 8) * DD + n0 + bcol;
    const int tx = tid & 15, ty = tid >> 4;
    float acc[8][8];
#pragma unroll
    for (int i = 0; i < 8; i++)
#pragma unroll
        for (int j = 0; j < 8; j++) acc[i][j] = 0.f;

    for (int k0 = 0; k0 < DD; k0 += 16) {
        float4 a1 = *(const float4*)(pA1 + k0);
        float4 a2 = *(const float4*)(pA2 + k0);
        float4 b1 = *(const float4*)(pB1 + (size_t)k0 * DD);
        float4 b2 = *(const float4*)(pB2 + (size_t)k0 * DD);
        __syncthreads();
        As[kc + 0][lr] = a1.x; As[kc + 1][lr] = a1.y; As[kc + 2][lr] = a1.z; As[kc + 3][lr] = a1.w;
        As[kc + 0][64 + lr] = a2.x; As[kc + 1][64 + lr] = a2.y; As[kc + 2][64 + lr] = a2.z; As[kc + 3][64 + lr] = a2.w;
        *(float4*)&Bs[bkr][bcol] = b1;
        *(float4*)&Bs[bkr + 8][bcol] = b2;
        __syncthreads();
#pragma unroll
        for (int k = 0; k < 16; k++) {
            float4 a0 = *(const float4*)&As[k][ty * 8];
            float4 a1v = *(const float4*)&As[k][ty * 8 + 4];
            float4 b0 = *(const float4*)&Bs[k][tx * 8];
            float4 b1v = *(const float4*)&Bs[k][tx * 8 + 4];
            float avr[8] = {a0.x, a0.y, a0.z, a0.w, a1v.x, a1v.y, a1v.z, a1v.w};
            float bvr[8] = {b0.x, b0.y, b0.z, b0.w, b1v.x, b1v.y, b1v.z, b1v.w};
#pragma unroll
            for (int i = 0; i < 8; i++)
#pragma unroll
                for (int j = 0; j < 8; j++) acc[i][j] += avr[i] * bvr[j];
        }
    }
    float sig = scal[0];
    float bo_[8];
#pragma unroll
    for (int j = 0; j < 8; j++) bo_[j] = bo[n0 + tx * 8 + j];
#pragma unroll
    for (int i = 0; i < 8; i++) {
        int r = row0 + ty * 8 + i;
        int b = r / PP, p = r - b * PP;
        size_t xoff = ((size_t)b * 577 + 1 + p) * DD + n0 + tx * 8;
        float4 x0 = *(const float4*)(x + xoff);
        float4 x1 = *(const float4*)(x + xoff + 4);
        const float* an = anco + b * DD + n0 + tx * 8;
        float4 a0 = *(const float4*)an;
        float4 a1 = *(const float4*)(an + 4);
        float* op = dout + OUT_OUT + xoff;
        *(float4*)op = make_float4(acc[i][0] + bo_[0] + x0.x + sig * a0.x,
                                   acc[i][1] + bo_[1] + x0.y + sig * a0.y,
                                   acc[i][2] + bo_[2] + x0.z + sig * a0.z,
                                   acc[i][3] + bo_[3] + x0.w + sig * a0.w);
        *(float4*)(op + 4) = make_float4(acc[i][4] + bo_[4] + x1.x + sig * a1.x,
                                         acc[i][5] + bo_[5] + x1.y + sig * a1.y,
                                         acc[i][6] + bo_[6] + x1.z + sig * a1.z,
                                         acc[i][7] + bo_[7] + x1.w + sig * a1.w);
    }
}

// ---------------------------------------------------------------------------
// 16) cls passthrough
// ---------------------------------------------------------------------------
__global__ void k_cls(const float* __restrict__ x, float* __restrict__ dout)
{
    int idx = blockIdx.x * 256 + threadIdx.x;  // < 32*768
    int b = idx / DD, d = idx - b * DD;
    dout[OUT_OUT + (size_t)b * 577 * DD + d] = x[(size_t)b * 577 * DD + d];
}

// ---------------------------------------------------------------------------
extern "C" void kernel_launch(void* const* d_in, const int* in_sizes, int n_in,
                              void* d_out, int out_size, void* d_ws, size_t ws_size,
                              hipStream_t stream)
{
    (void)in_sizes; (void)n_in; (void)out_size; (void)ws_size;
    const float* x   = (const float*)d_in[0];
    const float* fp  = (const float*)d_in[1];
    const float* Wq  = (const float*)d_in[2];
    const float* bq  = (const float*)d_in[3];
    const float* Wk  = (const float*)d_in[4];
    const float* bk  = (const float*)d_in[5];
    const float* Wv  = (const float*)d_in[6];
    const float* bv  = (const float*)d_in[7];
    const float* Wo  = (const float*)d_in[8];
    const float* bo  = (const float*)d_in[9];
    const float* Wqm = (const float*)d_in[10];
    const float* bqm = (const float*)d_in[11];
    const float* Wkm = (const float*)d_in[12];
    const float* bkm = (const float*)d_in[13];
    const float* Wvm = (const float*)d_in[14];
    const float* bvm = (const float*)d_in[15];
    const float* Wfo = (const float*)d_in[16];
    const float* bfo = (const float*)d_in[17];
    const float* ae  = (const float*)d_in[18];
    const float* AW  = (const float*)d_in[19];
    const float* Wab = (const float*)d_in[20];
    const float* bab = (const float*)d_in[21];
    const float* Wfp = (const float*)d_in[22];
    const float* bfp = (const float*)d_in[23];
    const float* aw  = (const float*)d_in[24];
    char* ws = (char*)d_ws;
    float* dout = (float*)d_out;

    double* qk64    = (double*)(ws + OFFB_QK64);
    double* sc64    = (double*)(ws + OFFB_SC64);
    float*  v32     = (float*)(ws + OFFB_V32);
    double* weqk64  = (double*)(ws + OFFB_WEQK64);
    float*  wev32   = (float*)(ws + OFFB_WEV32);
    float*  wot32   = (float*)(ws + OFFB_WOT32);
    double* cn64    = (double*)(ws + OFFB_CN64);
    double* biasqk  = (double*)(ws + OFFB_BIASQK64);
    float*  biasv   = (float*)(ws + OFFB_BIASV32);
    float*  scal32  = (float*)(ws + OFFB_SCAL32);
    float*  fpb32   = (float*)(ws + OFFB_FPB32);
    float*  pool32  = (float*)(ws + OFFB_POOL32);
    float*  feat32  = (float*)(ws + OFFB_FEAT32);
    float*  ancn32  = (float*)(ws + OFFB_ANCN32);
    float*  affs32  = (float*)(ws + OFFB_AFFS32);
    float*  aaff32  = (float*)(ws + OFFB_AAFF32);
    float*  preds32 = (float*)(ws + OFFB_PREDS32);
    float*  anco32  = (float*)(ws + OFFB_ANCO32);
    float*  routed  = (float*)(ws + OFFB_ROUTED32);   // aliases qk64 (dead by then)

    k_weffqk64<<<dim3(4608), dim3(256), 0, stream>>>(Wq, Wk, Wqm, Wkm, bqm, bkm, fp, weqk64);
    k_weffv32<<<dim3(2304), dim3(256), 0, stream>>>(Wv, Wvm, bvm, fp, wev32);
    k_setup64<<<dim3(1), dim3(640), 0, stream>>>(fp, Wfo, bfo, Wab, bab, bq, bk, bv, aw, ws);
    k_anchors<<<dim3(16), dim3(64), 0, stream>>>(ae, ancn32);
    k_gemm_qk64<<<dim3(24, 288), dim3(256), 0, stream>>>(x, weqk64, biasqk, qk64);
    k_norm64<<<dim3(9216), dim3(256), 0, stream>>>(qk64);
    k_gemm_v32<<<dim3(6, 144), dim3(256), 0, stream>>>(x, wev32, biasv, v32);
    k_gemm_scores64<<<dim3(9, 9, 32), dim3(256), 0, stream>>>(qk64, cn64, sc64);
    k_topk64<<<dim3(4608), dim3(256), 0, stream>>>(sc64, v32, routed, dout);
    k_pooled<<<dim3(3, 32), dim3(256), 0, stream>>>(x, pool32);
    k_featproj<<<dim3(32), dim3(256), 0, stream>>>(pool32, Wfp, bfp, feat32);
    k_affs<<<dim3(128), dim3(256), 0, stream>>>(feat32, ancn32, fpb32, affs32);
    k_affsm<<<dim3(32), dim3(64), 0, stream>>>(affs32, aaff32);
    k_preds<<<dim3(12, 16), dim3(256), 0, stream>>>(pool32, AW, preds32);
    k_anco<<<dim3(3, 32), dim3(256), 0, stream>>>(preds32, aaff32, anco32);
    k_wot<<<dim3(24, 24), dim3(32, 8), 0, stream>>>(Wo, wot32);
    k_gemm_out<<<dim3(6, 144), dim3(256), 0, stream>>>(routed, wot32, bo, x, anco32, scal32, dout);
    k_cls<<<dim3(96), dim3(256), 0, stream>>>(x, dout);
}

// Round 4
// 2724.239 us; speedup vs baseline: 1.0964x; 1.0964x over previous
//
#include <hip/hip_runtime.h>
#include <math.h>

#define DD 768
#define PP 576
#define BB 32
#define NROW (BB*PP)     // 18432
#define NA 16
#define NFP 64
#define KSEL 8
#define NEGV -1000000000.0

// ---- workspace BYTE offsets ----
#define OFFB_QK64     0ull            // 18432*1536*8 = 226492416
#define OFFB_SC64     226492416ull    // 32*576*576*8 = 84934656
#define OFFB_V32      311427072ull    // 18432*768*4 = 56623104
#define OFFB_WEQK64   368050176ull    // 768*1536*8 = 9437184
#define OFFB_WEV32    377487360ull    // 768*768*4
#define OFFB_WOT32    379846656ull    // 768*768*4
#define OFFB_CN64     382205952ull    // 576*8
#define OFFB_BIASQK64 382210560ull    // 1536*8
#define OFFB_BIASV32  382222848ull    // 768*4
#define OFFB_SCAL32   382225920ull    // 16*4
#define OFFB_FPB32    382225984ull    // 16*4
#define OFFB_POOL32   382226048ull    // 32*768*4
#define OFFB_FEAT32   382324352ull
#define OFFB_ANCN32   382422656ull    // 16*768*4
#define OFFB_AFFS32   382471808ull
#define OFFB_AAFF32   382473856ull
#define OFFB_PREDS32  382475904ull    // 32*16*768*4
#define OFFB_ANCO32   384048768ull
#define OFFB_ROUTED32 0ull            // aliases QK64 (dead after scores GEMM)
// total = 384147072 bytes (~366 MB)

// ---- d_out float offsets ----
#define OUT_ROUTES  0
#define OUT_WEIGHTS 147456
#define OUT_OUT     294912

__device__ __forceinline__ float wave_sum_f(float v) {
#pragma unroll
    for (int off = 32; off > 0; off >>= 1) v += __shfl_xor(v, off);
    return v;
}
__device__ __forceinline__ double wave_sum_d(double v) {
#pragma unroll
    for (int off = 32; off > 0; off >>= 1) v += __shfl_xor(v, off);
    return v;
}

// ---------------------------------------------------------------------------
// 1a) W_eff for q,k in f64
// ---------------------------------------------------------------------------
__global__ void k_weffqk64(const float* __restrict__ Wq, const float* __restrict__ Wk,
                           const float* __restrict__ Wqm, const float* __restrict__ Wkm,
                           const float* __restrict__ bqm, const float* __restrict__ bkm,
                           const float* __restrict__ fp, double* __restrict__ weff)
{
    int gid = blockIdx.x * 256 + threadIdx.x;   // < 2*589824
    int m = gid / (DD * DD);
    int e = gid - m * (DD * DD);
    const float* Wm = m ? Wkm : Wqm;
    const float* bm = m ? bkm : bqm;
    const float* W  = m ? Wk  : Wq;
    int d = e / DD, j = e - d * DD;
    const float4* wrow = (const float4*)(Wm + (size_t)e * NFP);
    const float4* f4 = (const float4*)fp;
    double dot = 0.0;
#pragma unroll
    for (int i = 0; i < 16; i++) {
        float4 a = wrow[i]; float4 b = f4[i];
        dot += (double)a.x * (double)b.x + (double)a.y * (double)b.y
             + (double)a.z * (double)b.z + (double)a.w * (double)b.w;
    }
    weff[(size_t)d * 1536 + m * DD + j] = (double)W[(size_t)j * DD + d] + 0.1 * (dot + (double)bm[e]);
}

// ---------------------------------------------------------------------------
// 1b) W_eff for v in f32
// ---------------------------------------------------------------------------
__global__ void k_weffv32(const float* __restrict__ Wv, const float* __restrict__ Wvm,
                          const float* __restrict__ bvm, const float* __restrict__ fp,
                          float* __restrict__ weff)
{
    int e = blockIdx.x * 256 + threadIdx.x;     // < 589824
    int d = e / DD, j = e - d * DD;
    const float4* wrow = (const float4*)(Wvm + (size_t)e * NFP);
    const float4* f4 = (const float4*)fp;
    float dot = 0.f;
#pragma unroll
    for (int i = 0; i < 16; i++) {
        float4 a = wrow[i]; float4 b = f4[i];
        dot += a.x * b.x + a.y * b.y + a.z * b.z + a.w * b.w;
    }
    weff[(size_t)d * DD + j] = Wv[(size_t)j * DD + d] + 0.1f * (dot + bvm[e]);
}

// ---------------------------------------------------------------------------
// 2) setup: cnorm (f64), biases, fp_bias, sigmoid(aw)
// ---------------------------------------------------------------------------
__global__ void k_setup64(const float* __restrict__ fp,
                          const float* __restrict__ Wfo, const float* __restrict__ bfo,
                          const float* __restrict__ Wab, const float* __restrict__ bab,
                          const float* __restrict__ bq, const float* __restrict__ bk,
                          const float* __restrict__ bv,
                          const float* __restrict__ aw, char* __restrict__ ws)
{
    double* cn = (double*)(ws + OFFB_CN64);
    double* biasqk = (double*)(ws + OFFB_BIASQK64);
    float* biasv = (float*)(ws + OFFB_BIASV32);
    float* scal = (float*)(ws + OFFB_SCAL32);
    float* fpb = (float*)(ws + OFFB_FPB32);
    __shared__ double shp[2];
    __shared__ double shc[PP];
    int t = threadIdx.x;
    if (t < 2) {
        double s = 0.0;
        for (int i = 0; i < NFP; i++) s += (double)Wfo[t * NFP + i] * (double)fp[i];
        shp[t] = s + (double)bfo[t];
    }
    if (t == 2) scal[0] = (float)(1.0 / (1.0 + exp(-(double)aw[0])));
    if (t >= 4 && t < 20) {
        int a = t - 4;
        float s = 0.f;
        for (int i = 0; i < NFP; i++) s += Wab[a * NFP + i] * fp[i];
        fpb[a] = s + bab[a];
    }
    for (int i = t; i < 1536; i += 640) biasqk[i] = (double)((i < DD) ? bq[i] : bk[i - DD]);
    for (int i = t; i < DD; i += 640) biasv[i] = bv[i];
    __syncthreads();
    double scale = 2.0 / (1.0 + exp(-shp[0])) + 0.5;
    double shift = tanh(shp[1]) * 24.0;
    if (t < PP) {
        int xg = t % 24, yg = t / 24;
        int s = xg + yg;
        double cant = (double)(s * (s + 1) / 2 + yg);
        shc[t] = cant * scale + shift;
    }
    __syncthreads();
    if (t == 0) {
        double mx = shc[0];
        for (int i = 1; i < PP; i++) mx = fmax(mx, shc[i]);
        shp[0] = fmax(mx, 1.0);
    }
    __syncthreads();
    if (t < PP) cn[t] = shc[t] / shp[0];
}

// ---------------------------------------------------------------------------
// 3) l2-normalize anchor_embeds rows
// ---------------------------------------------------------------------------
__global__ void k_anchors(const float* __restrict__ ae, float* __restrict__ ancn)
{
    int a = blockIdx.x, lane = threadIdx.x;
    const float4* row = (const float4*)(ae + (size_t)a * DD);
    float4 v[3]; float ss = 0.f;
#pragma unroll
    for (int c = 0; c < 3; c++) {
        v[c] = row[c * 64 + lane];
        ss += v[c].x * v[c].x + v[c].y * v[c].y + v[c].z * v[c].z + v[c].w * v[c].w;
    }
    ss = wave_sum_f(ss);
    float den = fmaxf(sqrtf(ss), 1e-12f);
    float4* o = (float4*)(ancn + (size_t)a * DD);
#pragma unroll
    for (int c = 0; c < 3; c++)
        o[c * 64 + lane] = make_float4(v[c].x / den, v[c].y / den, v[c].z / den, v[c].w / den);
}

// ---------------------------------------------------------------------------
// 4) q,k GEMM in f64, 64x64x16 tile, 4x4 micro.
//    B-fragment columns remapped to {2tx,2tx+1, 2tx+32,2tx+33}:
//    double2 read at word 4*tx marches lanes through all 32 banks (conflict-free).
// ---------------------------------------------------------------------------
__launch_bounds__(256)
__global__ void k_gemm_qk64(const float* __restrict__ x, const double* __restrict__ weff,
                            const double* __restrict__ bias, double* __restrict__ qk)
{
    __shared__ double As[16][66];
    __shared__ double Bs[16][66];
    const int tid = threadIdx.x;
    const int n0 = blockIdx.x * 64;
    const int row0 = blockIdx.y * 64;
    const int lr = tid >> 2;            // 0..63
    const int kc = (tid & 3) * 4;       // 0,4,8,12
    const int r = row0 + lr;
    const float* pA = x + (size_t)(r + r / PP + 1) * DD + kc;
    const int bkr = tid >> 4;           // 0..15 (k row)
    const int bcol = (tid & 15) * 4;    // 0..60
    const double* pB = weff + (size_t)bkr * 1536 + n0 + bcol;
    const int tx = tid & 15, ty = tid >> 4;
    double acc[4][4];
#pragma unroll
    for (int i = 0; i < 4; i++)
#pragma unroll
        for (int j = 0; j < 4; j++) acc[i][j] = 0.0;

    for (int k0 = 0; k0 < DD; k0 += 16) {
        float4 a = *(const float4*)(pA + k0);
        double2 b0 = *(const double2*)(pB + (size_t)k0 * 1536);
        double2 b1 = *(const double2*)(pB + (size_t)k0 * 1536 + 2);
        __syncthreads();
        As[kc + 0][lr] = (double)a.x; As[kc + 1][lr] = (double)a.y;
        As[kc + 2][lr] = (double)a.z; As[kc + 3][lr] = (double)a.w;
        *(double2*)&Bs[bkr][bcol] = b0;
        *(double2*)&Bs[bkr][bcol + 2] = b1;
        __syncthreads();
#pragma unroll
        for (int k = 0; k < 16; k++) {
            double2 a01 = *(const double2*)&As[k][ty * 4];
            double2 a23 = *(const double2*)&As[k][ty * 4 + 2];
            double2 b01 = *(const double2*)&Bs[k][tx * 2];        // cols 2tx,2tx+1
            double2 b23 = *(const double2*)&Bs[k][tx * 2 + 32];   // cols 2tx+32,2tx+33
            double av[4] = {a01.x, a01.y, a23.x, a23.y};
            double bv[4] = {b01.x, b01.y, b23.x, b23.y};
#pragma unroll
            for (int i = 0; i < 4; i++)
#pragma unroll
                for (int j = 0; j < 4; j++) acc[i][j] = fma(av[i], bv[j], acc[i][j]);
        }
    }
#pragma unroll
    for (int i = 0; i < 4; i++) {
        int rr = row0 + ty * 4 + i;
        double* op0 = qk + (size_t)rr * 1536 + n0 + tx * 2;
        double* op1 = qk + (size_t)rr * 1536 + n0 + 32 + tx * 2;
        op0[0] = acc[i][0] + bias[n0 + tx * 2];
        op0[1] = acc[i][1] + bias[n0 + tx * 2 + 1];
        op1[0] = acc[i][2] + bias[n0 + 32 + tx * 2];
        op1[1] = acc[i][3] + bias[n0 + 32 + tx * 2 + 1];
    }
}

// ---------------------------------------------------------------------------
// 5) f64 l2-normalize q,k rows in-place
// ---------------------------------------------------------------------------
__launch_bounds__(256)
__global__ void k_norm64(double* __restrict__ qk)
{
    const int tid = threadIdx.x, wv = tid >> 6, lane = tid & 63;
    const int task = blockIdx.x * 4 + wv;     // < 36864
    const int row = task >> 1, mat = task & 1;
    double2* p = (double2*)(qk + (size_t)row * 1536 + mat * DD);
    double2 v[6]; double ss = 0.0;
#pragma unroll
    for (int c = 0; c < 6; c++) {
        v[c] = p[c * 64 + lane];
        ss += v[c].x * v[c].x + v[c].y * v[c].y;
    }
    ss = wave_sum_d(ss);
    double den = fmax(sqrt(ss), 1e-12);
#pragma unroll
    for (int c = 0; c < 6; c++) {
        v[c].x /= den; v[c].y /= den;
        p[c * 64 + lane] = v[c];
    }
}

// ---------------------------------------------------------------------------
// 6) v GEMM f32, 128x128x16, 8x8 micro; B cols remapped {4tx..+3, 64+4tx..+3}
// ---------------------------------------------------------------------------
__launch_bounds__(256)
__global__ void k_gemm_v32(const float* __restrict__ x, const float* __restrict__ weff,
                           const float* __restrict__ biasv, float* __restrict__ vout)
{
    __shared__ float As[16][132];
    __shared__ float Bs[16][132];
    const int tid = threadIdx.x;
    const int n0 = blockIdx.x * 128;
    const int row0 = blockIdx.y * 128;
    const int lr = tid >> 2;
    const int kc = (tid & 3) * 4;
    const int r1 = row0 + lr, r2 = r1 + 64;
    const float* pA1 = x + (size_t)(r1 + r1 / PP + 1) * DD + kc;
    const float* pA2 = x + (size_t)(r2 + r2 / PP + 1) * DD + kc;
    const int bkr = tid >> 5;
    const int bcol = (tid & 31) * 4;
    const float* pB1 = weff + (size_t)bkr * DD + n0 + bcol;
    const float* pB2 = weff + (size_t)(bkr + 8) * DD + n0 + bcol;
    const int tx = tid & 15, ty = tid >> 4;
    float acc[8][8];
#pragma unroll
    for (int i = 0; i < 8; i++)
#pragma unroll
        for (int j = 0; j < 8; j++) acc[i][j] = 0.f;

    for (int k0 = 0; k0 < DD; k0 += 16) {
        float4 a1 = *(const float4*)(pA1 + k0);
        float4 a2 = *(const float4*)(pA2 + k0);
        float4 b1 = *(const float4*)(pB1 + (size_t)k0 * DD);
        float4 b2 = *(const float4*)(pB2 + (size_t)k0 * DD);
        __syncthreads();
        As[kc + 0][lr] = a1.x; As[kc + 1][lr] = a1.y; As[kc + 2][lr] = a1.z; As[kc + 3][lr] = a1.w;
        As[kc + 0][64 + lr] = a2.x; As[kc + 1][64 + lr] = a2.y; As[kc + 2][64 + lr] = a2.z; As[kc + 3][64 + lr] = a2.w;
        *(float4*)&Bs[bkr][bcol] = b1;
        *(float4*)&Bs[bkr + 8][bcol] = b2;
        __syncthreads();
#pragma unroll
        for (int k = 0; k < 16; k++) {
            float4 a0 = *(const float4*)&As[k][ty * 8];
            float4 a1v = *(const float4*)&As[k][ty * 8 + 4];
            float4 b0 = *(const float4*)&Bs[k][tx * 4];        // cols 4tx..4tx+3
            float4 b1v = *(const float4*)&Bs[k][tx * 4 + 64];  // cols 64+4tx..
            float av[8] = {a0.x, a0.y, a0.z, a0.w, a1v.x, a1v.y, a1v.z, a1v.w};
            float bv[8] = {b0.x, b0.y, b0.z, b0.w, b1v.x, b1v.y, b1v.z, b1v.w};
#pragma unroll
            for (int i = 0; i < 8; i++)
#pragma unroll
                for (int j = 0; j < 8; j++) acc[i][j] += av[i] * bv[j];
        }
    }
    float bb_[8];
#pragma unroll
    for (int j = 0; j < 4; j++) bb_[j] = biasv[n0 + tx * 4 + j];
#pragma unroll
    for (int j = 0; j < 4; j++) bb_[4 + j] = biasv[n0 + 64 + tx * 4 + j];
#pragma unroll
    for (int i = 0; i < 8; i++) {
        int rr = row0 + ty * 8 + i;
        float* op0 = vout + (size_t)rr * DD + n0 + tx * 4;
        float* op1 = vout + (size_t)rr * DD + n0 + 64 + tx * 4;
        *(float4*)op0 = make_float4(acc[i][0] + bb_[0], acc[i][1] + bb_[1],
                                    acc[i][2] + bb_[2], acc[i][3] + bb_[3]);
        *(float4*)op1 = make_float4(acc[i][4] + bb_[4], acc[i][5] + bb_[5],
                                    acc[i][6] + bb_[6], acc[i][7] + bb_[7]);
    }
}

// ---------------------------------------------------------------------------
// 7) scores GEMM f64; B-fragment remap as in qk64
// ---------------------------------------------------------------------------
__launch_bounds__(256)
__global__ void k_gemm_scores64(const double* __restrict__ qk, const double* __restrict__ cn,
                                double* __restrict__ scores)
{
    __shared__ double As[16][66];
    __shared__ double Bs[16][66];
    const int bz = blockIdx.z;
    const int row0 = blockIdx.y * 64, col0 = blockIdx.x * 64;
    const int tid = threadIdx.x;
    const int lr = tid >> 2;
    const int kc = (tid & 3) * 4;
    const double* pA = qk + (size_t)(bz * PP + row0 + lr) * 1536 + kc;        // q
    const double* pB = qk + (size_t)(bz * PP + col0 + lr) * 1536 + DD + kc;   // k
    const int tx = tid & 15, ty = tid >> 4;
    double acc[4][4];
#pragma unroll
    for (int i = 0; i < 4; i++)
#pragma unroll
        for (int j = 0; j < 4; j++) acc[i][j] = 0.0;

    for (int k0 = 0; k0 < DD; k0 += 16) {
        double2 a0 = *(const double2*)(pA + k0);
        double2 a1 = *(const double2*)(pA + k0 + 2);
        double2 b0 = *(const double2*)(pB + k0);
        double2 b1 = *(const double2*)(pB + k0 + 2);
        __syncthreads();
        As[kc + 0][lr] = a0.x; As[kc + 1][lr] = a0.y; As[kc + 2][lr] = a1.x; As[kc + 3][lr] = a1.y;
        Bs[kc + 0][lr] = b0.x; Bs[kc + 1][lr] = b0.y; Bs[kc + 2][lr] = b1.x; Bs[kc + 3][lr] = b1.y;
        __syncthreads();
#pragma unroll
        for (int k = 0; k < 16; k++) {
            double2 a01 = *(const double2*)&As[k][ty * 4];
            double2 a23 = *(const double2*)&As[k][ty * 4 + 2];
            double2 b01 = *(const double2*)&Bs[k][tx * 2];        // cols 2tx,2tx+1
            double2 b23 = *(const double2*)&Bs[k][tx * 2 + 32];   // cols 2tx+32,+33
            double av[4] = {a01.x, a01.y, a23.x, a23.y};
            double bv[4] = {b01.x, b01.y, b23.x, b23.y};
#pragma unroll
            for (int i = 0; i < 4; i++)
#pragma unroll
                for (int j = 0; j < 4; j++) acc[i][j] = fma(av[i], bv[j], acc[i][j]);
        }
    }
#pragma unroll
    for (int i = 0; i < 4; i++) {
        int p = row0 + ty * 4 + i;
        double cp = cn[p];
        double* op = scores + ((size_t)bz * PP + p) * PP;
        int j0 = col0 + tx * 2;
        int j1 = col0 + 32 + tx * 2;
        double s0 = acc[i][0] + 0.3 * (1.0 - fabs(cp - cn[j0]));
        double s1 = acc[i][1] + 0.3 * (1.0 - fabs(cp - cn[j0 + 1]));
        double s2 = acc[i][2] + 0.3 * (1.0 - fabs(cp - cn[j1]));
        double s3 = acc[i][3] + 0.3 * (1.0 - fabs(cp - cn[j1 + 1]));
        op[j0]     = (p == j0)     ? NEGV : s0;
        op[j0 + 1] = (p == j0 + 1) ? NEGV : s1;
        op[j1]     = (p == j1)     ? NEGV : s2;
        op[j1 + 1] = (p == j1 + 1) ? NEGV : s3;
    }
}

// ---------------------------------------------------------------------------
// 8) top-k=8 f64 (stable ties), f64 softmax, routed gather (wave per row)
// ---------------------------------------------------------------------------
__launch_bounds__(256)
__global__ void k_topk64(const double* __restrict__ scores, const float* __restrict__ v32,
                         float* __restrict__ routed, float* __restrict__ dout)
{
    const int tid = threadIdx.x;
    const int wv = tid >> 6, lane = tid & 63;
    const int row = blockIdx.x * 4 + wv;
    const int b = row / PP;
    const double* srow = scores + (size_t)row * PP;
    double cand[9];
#pragma unroll
    for (int c = 0; c < 9; c++) cand[c] = srow[c * 64 + lane] / 0.1;   // scores/TEMP, f64
    double vals[8]; int idxs[8];
#pragma unroll
    for (int k = 0; k < KSEL; k++) {
        double bvv = -1.0e300; int bj = 1 << 29;
#pragma unroll
        for (int c = 0; c < 9; c++) {
            if (cand[c] > bvv) { bvv = cand[c]; bj = c * 64 + lane; }
        }
#pragma unroll
        for (int off = 32; off > 0; off >>= 1) {
            double ov = __shfl_xor(bvv, off);
            int oj = __shfl_xor(bj, off);
            if (ov > bvv || (ov == bvv && oj < bj)) { bvv = ov; bj = oj; }
        }
        vals[k] = bvv; idxs[k] = bj;
        int slot = bj >> 6;
#pragma unroll
        for (int c = 0; c < 9; c++)
            if (c == slot && (bj & 63) == lane) cand[c] = -1.0e300;
    }
    double mx = vals[0];
    double e[8]; double s = 0.0;
#pragma unroll
    for (int k = 0; k < 8; k++) { e[k] = exp(vals[k] - mx); s += e[k]; }
    float w8[8];
#pragma unroll
    for (int k = 0; k < 8; k++) {
        w8[k] = (float)(e[k] / s);
        if (lane == k) {
            dout[OUT_ROUTES + (size_t)row * 8 + k] = (float)idxs[k];
            dout[OUT_WEIGHTS + (size_t)row * 8 + k] = w8[k];
        }
    }
    float4 av[3];
#pragma unroll
    for (int c = 0; c < 3; c++) av[c] = make_float4(0.f, 0.f, 0.f, 0.f);
#pragma unroll
    for (int k = 0; k < 8; k++) {
        float w = w8[k];
        const float4* vr = (const float4*)(v32 + (size_t)(b * PP + idxs[k]) * DD);
#pragma unroll
        for (int c = 0; c < 3; c++) {
            float4 vv = vr[c * 64 + lane];
            av[c].x += w * vv.x; av[c].y += w * vv.y; av[c].z += w * vv.z; av[c].w += w * vv.w;
        }
    }
    float4* orow = (float4*)(routed + (size_t)row * DD);
#pragma unroll
    for (int c = 0; c < 3; c++) orow[c * 64 + lane] = av[c];
}

// ---------------------------------------------------------------------------
// 9) pooled = mean over patches
// ---------------------------------------------------------------------------
__global__ void k_pooled(const float* __restrict__ x, float* __restrict__ pooled)
{
    int b = blockIdx.y;
    int d = blockIdx.x * 256 + threadIdx.x;
    const float* base = x + ((size_t)b * 577 + 1) * DD + d;
    float s = 0.f;
    for (int p = 0; p < PP; p++) s += base[(size_t)p * DD];
    pooled[b * DD + d] = s / 576.0f;
}

// ---------------------------------------------------------------------------
// 10) feat_proj = l2(pooled @ Wfp.T + bfp)
// ---------------------------------------------------------------------------
__global__ void k_featproj(const float* __restrict__ pooled, const float* __restrict__ Wfp,
                           const float* __restrict__ bfp, float* __restrict__ feat)
{
    __shared__ float ps[DD];
    __shared__ float red[256];
    int b = blockIdx.x, t = threadIdx.x;
    for (int i = t; i < DD; i += 256) ps[i] = pooled[b * DD + i];
    __syncthreads();
    float out[3]; float ss = 0.f;
#pragma unroll
    for (int c = 0; c < 3; c++) {
        int j = c * 256 + t;
        const float4* wr = (const float4*)(Wfp + (size_t)j * DD);
        float s = 0.f;
        for (int i = 0; i < 192; i++) {
            float4 w4 = wr[i];
            s += ps[4 * i] * w4.x + ps[4 * i + 1] * w4.y + ps[4 * i + 2] * w4.z + ps[4 * i + 3] * w4.w;
        }
        s += bfp[j];
        out[c] = s; ss += s * s;
    }
    red[t] = ss; __syncthreads();
    for (int st = 128; st > 0; st >>= 1) {
        if (t < st) red[t] += red[t + st];
        __syncthreads();
    }
    float den = fmaxf(sqrtf(red[0]), 1e-12f);
#pragma unroll
    for (int c = 0; c < 3; c++) feat[b * DD + c * 256 + t] = out[c] / den;
}

// ---------------------------------------------------------------------------
// 11) anchor affinity + softmax
// ---------------------------------------------------------------------------
__global__ void k_affs(const float* __restrict__ feat, const float* __restrict__ ancn,
                       const float* __restrict__ fpb, float* __restrict__ affs)
{
    int tid = threadIdx.x, wv = tid >> 6, lane = tid & 63;
    int wid = blockIdx.x * 4 + wv;
    int b = wid >> 4, a = wid & 15;
    const float4* f4 = (const float4*)(feat + (size_t)b * DD);
    const float4* a4 = (const float4*)(ancn + (size_t)a * DD);
    float s = 0.f;
#pragma unroll
    for (int c = 0; c < 3; c++) {
        float4 fv = f4[c * 64 + lane], av = a4[c * 64 + lane];
        s += fv.x * av.x + fv.y * av.y + fv.z * av.z + fv.w * av.w;
    }
    s = wave_sum_f(s);
    if (lane == 0) affs[b * NA + a] = s + 0.3f * fpb[a];
}

__global__ void k_affsm(const float* __restrict__ affs, float* __restrict__ aaff)
{
    int b = blockIdx.x, lane = threadIdx.x;
    float v = affs[b * NA + (lane & 15)];
    float m = v;
#pragma unroll
    for (int off = 8; off > 0; off >>= 1) m = fmaxf(m, __shfl_xor(m, off));
    float e = expf(v - m);
    float s = e;
#pragma unroll
    for (int off = 8; off > 0; off >>= 1) s += __shfl_xor(s, off);
    if (lane < NA) aaff[b * NA + lane] = e / s;
}

// ---------------------------------------------------------------------------
// 12) anchor_preds[b,a,e] = pooled[b]·AW[a,e,:]
// ---------------------------------------------------------------------------
__launch_bounds__(256)
__global__ void k_preds(const float* __restrict__ pooled, const float* __restrict__ AW,
                        float* __restrict__ preds)
{
    __shared__ float AWs[64][65];
    __shared__ float ps[32][65];
    const int a = blockIdx.y;
    const int e0 = blockIdx.x * 64;
    const int t = threadIdx.x;
    const int eloc = t & 63, bgrp = t >> 6;
    float acc[8];
#pragma unroll
    for (int i = 0; i < 8; i++) acc[i] = 0.f;
    for (int d0 = 0; d0 < DD; d0 += 64) {
        __syncthreads();
#pragma unroll
        for (int i = 0; i < 16; i++) {
            int lin = t + i * 256;
            int ei = lin >> 6, dd = lin & 63;
            AWs[ei][dd] = AW[((size_t)a * DD + e0 + ei) * DD + d0 + dd];
        }
#pragma unroll
        for (int i = 0; i < 8; i++) {
            int lin = t + i * 256;
            int bb2 = lin >> 6, dd = lin & 63;
            ps[bb2][dd] = pooled[bb2 * DD + d0 + dd];
        }
        __syncthreads();
        for (int dd = 0; dd < 64; dd++) {
            float w = AWs[eloc][dd];
#pragma unroll
            for (int bb2 = 0; bb2 < 8; bb2++) acc[bb2] += ps[bgrp * 8 + bb2][dd] * w;
        }
    }
#pragma unroll
    for (int bb2 = 0; bb2 < 8; bb2++)
        preds[((size_t)(bgrp * 8 + bb2) * NA + a) * DD + e0 + eloc] = acc[bb2];
}

// ---------------------------------------------------------------------------
// 13) anchor_out[b,e] = sum_a aaff[b,a]*preds[b,a,e]
// ---------------------------------------------------------------------------
__global__ void k_anco(const float* __restrict__ preds, const float* __restrict__ aaff,
                       float* __restrict__ anco)
{
    int b = blockIdx.y;
    int e = blockIdx.x * 256 + threadIdx.x;
    float s = 0.f;
#pragma unroll
    for (int a = 0; a < NA; a++) s += aaff[b * NA + a] * preds[((size_t)b * NA + a) * DD + e];
    anco[b * DD + e] = s;
}

// ---------------------------------------------------------------------------
// 14) transpose Wo
// ---------------------------------------------------------------------------
__global__ void k_wot(const float* __restrict__ Wo, float* __restrict__ wot)
{
    __shared__ float tile[32][33];
    int tx = threadIdx.x, ty = threadIdx.y;
    int j0 = blockIdx.y * 32, d0 = blockIdx.x * 32;
#pragma unroll
    for (int i = 0; i < 4; i++) tile[ty + i * 8][tx] = Wo[(size_t)(j0 + ty + i * 8) * DD + d0 + tx];
    __syncthreads();
#pragma unroll
    for (int i = 0; i < 4; i++) wot[(size_t)(d0 + ty + i * 8) * DD + j0 + tx] = tile[tx][ty + i * 8];
}

// ---------------------------------------------------------------------------
// 15) out GEMM: routed @ WoT + bo + patches + sig*anchor_out; B cols remapped
// ---------------------------------------------------------------------------
__launch_bounds__(256)
__global__ void k_gemm_out(const float* __restrict__ routed, const float* __restrict__ wot,
                           const float* __restrict__ bo, const float* __restrict__ x,
                           const float* __restrict__ anco, const float* __restrict__ scal,
                           float* __restrict__ dout)
{
    __shared__ float As[16][132];
    __shared__ float Bs[16][132];
    const int tid = threadIdx.x;
    const int n0 = blockIdx.x * 128;
    const int row0 = blockIdx.y * 128;
    const int lr = tid >> 2;
    const int kc = (tid & 3) * 4;
    const float* pA1 = routed + (size_t)(row0 + lr) * DD + kc;
    const float* pA2 = routed + (size_t)(row0 + 64 + lr) * DD + kc;
    const int bkr = tid >> 5;
    const int bcol = (tid & 31) * 4;
    const float* pB1 = wot + (size_t)bkr * DD + n0 + bcol;
    const float* pB2 = wot + (size_t)(bkr + 8) * DD + n0 + bcol;
    const int tx = tid & 15, ty = tid >> 4;
    float acc[8][8];
#pragma unroll
    for (int i = 0; i < 8; i++)
#pragma unroll
        for (int j = 0; j < 8; j++) acc[i][j] = 0.f;

    for (int k0 = 0; k0 < DD; k0 += 16) {
        float4 a1 = *(const float4*)(pA1 + k0);
        float4 a2 = *(const float4*)(pA2 + k0);
        float4 b1 = *(const float4*)(pB1 + (size_t)k0 * DD);
        float4 b2 = *(const float4*)(pB2 + (size_t)k0 * DD);
        __syncthreads();
        As[kc + 0][lr] = a1.x; As[kc + 1][lr] = a1.y; As[kc + 2][lr] = a1.z; As[kc + 3][lr] = a1.w;
        As[kc + 0][64 + lr] = a2.x; As[kc + 1][64 + lr] = a2.y; As[kc + 2][64 + lr] = a2.z; As[kc + 3][64 + lr] = a2.w;
        *(float4*)&Bs[bkr][bcol] = b1;
        *(float4*)&Bs[bkr + 8][bcol] = b2;
        __syncthreads();
#pragma unroll
        for (int k = 0; k < 16; k++) {
            float4 a0 = *(const float4*)&As[k][ty * 8];
            float4 a1v = *(const float4*)&As[k][ty * 8 + 4];
            float4 b0 = *(const float4*)&Bs[k][tx * 4];
            float4 b1v = *(const float4*)&Bs[k][tx * 4 + 64];
            float avr[8] = {a0.x, a0.y, a0.z, a0.w, a1v.x, a1v.y, a1v.z, a1v.w};
            float bvr[8] = {b0.x, b0.y, b0.z, b0.w, b1v.x, b1v.y, b1v.z, b1v.w};
#pragma unroll
            for (int i = 0; i < 8; i++)
#pragma unroll
                for (int j = 0; j < 8; j++) acc[i][j] += avr[i] * bvr[j];
        }
    }
    float sig = scal[0];
    float bo_[8];
#pragma unroll
    for (int j = 0; j < 4; j++) bo_[j] = bo[n0 + tx * 4 + j];
#pragma unroll
    for (int j = 0; j < 4; j++) bo_[4 + j] = bo[n0 + 64 + tx * 4 + j];
#pragma unroll
    for (int i = 0; i < 8; i++) {
        int r = row0 + ty * 8 + i;
        int b = r / PP, p = r - b * PP;
        size_t base = ((size_t)b * 577 + 1 + p) * DD;
        size_t xo0 = base + n0 + tx * 4;
        size_t xo1 = base + n0 + 64 + tx * 4;
        float4 x0 = *(const float4*)(x + xo0);
        float4 x1 = *(const float4*)(x + xo1);
        float4 a0 = *(const float4*)(anco + b * DD + n0 + tx * 4);
        float4 a1 = *(const float4*)(anco + b * DD + n0 + 64 + tx * 4);
        *(float4*)(dout + OUT_OUT + xo0) = make_float4(
            acc[i][0] + bo_[0] + x0.x + sig * a0.x,
            acc[i][1] + bo_[1] + x0.y + sig * a0.y,
            acc[i][2] + bo_[2] + x0.z + sig * a0.z,
            acc[i][3] + bo_[3] + x0.w + sig * a0.w);
        *(float4*)(dout + OUT_OUT + xo1) = make_float4(
            acc[i][4] + bo_[4] + x1.x + sig * a1.x,
            acc[i][5] + bo_[5] + x1.y + sig * a1.y,
            acc[i][6] + bo_[6] + x1.z + sig * a1.z,
            acc[i][7] + bo_[7] + x1.w + sig * a1.w);
    }
}

// ---------------------------------------------------------------------------
// 16) cls passthrough
// ---------------------------------------------------------------------------
__global__ void k_cls(const float* __restrict__ x, float* __restrict__ dout)
{
    int idx = blockIdx.x * 256 + threadIdx.x;  // < 32*768
    int b = idx / DD, d = idx - b * DD;
    dout[OUT_OUT + (size_t)b * 577 * DD + d] = x[(size_t)b * 577 * DD + d];
}

// ---------------------------------------------------------------------------
extern "C" void kernel_launch(void* const* d_in, const int* in_sizes, int n_in,
                              void* d_out, int out_size, void* d_ws, size_t ws_size,
                              hipStream_t stream)
{
    (void)in_sizes; (void)n_in; (void)out_size; (void)ws_size;
    const float* x   = (const float*)d_in[0];
    const float* fp  = (const float*)d_in[1];
    const float* Wq  = (const float*)d_in[2];
    const float* bq  = (const float*)d_in[3];
    const float* Wk  = (const float*)d_in[4];
    const float* bk  = (const float*)d_in[5];
    const float* Wv  = (const float*)d_in[6];
    const float* bv  = (const float*)d_in[7];
    const float* Wo  = (const float*)d_in[8];
    const float* bo  = (const float*)d_in[9];
    const float* Wqm = (const float*)d_in[10];
    const float* bqm = (const float*)d_in[11];
    const float* Wkm = (const float*)d_in[12];
    const float* bkm = (const float*)d_in[13];
    const float* Wvm = (const float*)d_in[14];
    const float* bvm = (const float*)d_in[15];
    const float* Wfo = (const float*)d_in[16];
    const float* bfo = (const float*)d_in[17];
    const float* ae  = (const float*)d_in[18];
    const float* AW  = (const float*)d_in[19];
    const float* Wab = (const float*)d_in[20];
    const float* bab = (const float*)d_in[21];
    const float* Wfp = (const float*)d_in[22];
    const float* bfp = (const float*)d_in[23];
    const float* aw  = (const float*)d_in[24];
    char* ws = (char*)d_ws;
    float* dout = (float*)d_out;

    double* qk64    = (double*)(ws + OFFB_QK64);
    double* sc64    = (double*)(ws + OFFB_SC64);
    float*  v32     = (float*)(ws + OFFB_V32);
    double* weqk64  = (double*)(ws + OFFB_WEQK64);
    float*  wev32   = (float*)(ws + OFFB_WEV32);
    float*  wot32   = (float*)(ws + OFFB_WOT32);
    double* cn64    = (double*)(ws + OFFB_CN64);
    double* biasqk  = (double*)(ws + OFFB_BIASQK64);
    float*  biasv   = (float*)(ws + OFFB_BIASV32);
    float*  scal32  = (float*)(ws + OFFB_SCAL32);
    float*  fpb32   = (float*)(ws + OFFB_FPB32);
    float*  pool32  = (float*)(ws + OFFB_POOL32);
    float*  feat32  = (float*)(ws + OFFB_FEAT32);
    float*  ancn32  = (float*)(ws + OFFB_ANCN32);
    float*  affs32  = (float*)(ws + OFFB_AFFS32);
    float*  aaff32  = (float*)(ws + OFFB_AAFF32);
    float*  preds32 = (float*)(ws + OFFB_PREDS32);
    float*  anco32  = (float*)(ws + OFFB_ANCO32);
    float*  routed  = (float*)(ws + OFFB_ROUTED32);   // aliases qk64 (dead by then)

    k_weffqk64<<<dim3(4608), dim3(256), 0, stream>>>(Wq, Wk, Wqm, Wkm, bqm, bkm, fp, weqk64);
    k_weffv32<<<dim3(2304), dim3(256), 0, stream>>>(Wv, Wvm, bvm, fp, wev32);
    k_setup64<<<dim3(1), dim3(640), 0, stream>>>(fp, Wfo, bfo, Wab, bab, bq, bk, bv, aw, ws);
    k_anchors<<<dim3(16), dim3(64), 0, stream>>>(ae, ancn32);
    k_gemm_qk64<<<dim3(24, 288), dim3(256), 0, stream>>>(x, weqk64, biasqk, qk64);
    k_norm64<<<dim3(9216), dim3(256), 0, stream>>>(qk64);
    k_gemm_v32<<<dim3(6, 144), dim3(256), 0, stream>>>(x, wev32, biasv, v32);
    k_gemm_scores64<<<dim3(9, 9, 32), dim3(256), 0, stream>>>(qk64, cn64, sc64);
    k_topk64<<<dim3(4608), dim3(256), 0, stream>>>(sc64, v32, routed, dout);
    k_pooled<<<dim3(3, 32), dim3(256), 0, stream>>>(x, pool32);
    k_featproj<<<dim3(32), dim3(256), 0, stream>>>(pool32, Wfp, bfp, feat32);
    k_affs<<<dim3(128), dim3(256), 0, stream>>>(feat32, ancn32, fpb32, affs32);
    k_affsm<<<dim3(32), dim3(64), 0, stream>>>(affs32, aaff32);
    k_preds<<<dim3(12, 16), dim3(256), 0, stream>>>(pool32, AW, preds32);
    k_anco<<<dim3(3, 32), dim3(256), 0, stream>>>(preds32, aaff32, anco32);
    k_wot<<<dim3(24, 24), dim3(32, 8), 0, stream>>>(Wo, wot32);
    k_gemm_out<<<dim3(6, 144), dim3(256), 0, stream>>>(routed, wot32, bo, x, anco32, scal32, dout);
    k_cls<<<dim3(96), dim3(256), 0, stream>>>(x, dout);
}